// Round 12
// baseline (137.237 us; speedup 1.0000x reference)
//
#include <hip/hip_runtime.h>
#include <stdint.h>

typedef __bf16 bf16x8 __attribute__((ext_vector_type(8)));
typedef __bf16 bf16x2 __attribute__((ext_vector_type(2)));
typedef float f32x4 __attribute__((ext_vector_type(4)));
typedef float f32x16 __attribute__((ext_vector_type(16)));
typedef unsigned short ushort_t;
typedef unsigned int uint;
typedef uint uint4v __attribute__((ext_vector_type(4)));

#define SEQ    2048
#define DMODEL 1024
#define NHEAD  16
#define DKH    64
#define NBATCH 2
#define MROWS  (NBATCH*SEQ)   // 4096
#define LOG2E  1.44269504088896340736f

__device__ __forceinline__ uint pk2(float a, float b) {
  bf16x2 t; t[0] = (__bf16)a; t[1] = (__bf16)b;
  return __builtin_bit_cast(uint, t);
}
__device__ __forceinline__ ushort_t b1(float a) {
  return __builtin_bit_cast(ushort_t, (__bf16)a);
}
__device__ __forceinline__ float fexp2(float x) {
#if __has_builtin(__builtin_amdgcn_exp2f)
  return __builtin_amdgcn_exp2f(x);
#else
  return exp2f(x);
#endif
}

__device__ __forceinline__ void gload16(const void* g, void* l) {
  __builtin_amdgcn_global_load_lds(
      (const __attribute__((address_space(1))) void*)g,
      (__attribute__((address_space(3))) void*)l, 16, 0, 0);
}

__device__ __forceinline__ f32x4 mfma16(bf16x8 a, bf16x8 b, f32x4 c) {
  return __builtin_amdgcn_mfma_f32_16x16x32_bf16(a, b, c, 0, 0, 0);
}
__device__ __forceinline__ f32x16 mfma32(bf16x8 a, bf16x8 b, f32x16 c) {
  return __builtin_amdgcn_mfma_f32_32x32x16_bf16(a, b, c, 0, 0, 0);
}

// ---------------- fused fp32 -> bf16 convert ----------------
__global__ __launch_bounds__(256) void cvt_all(
    const float* __restrict__ x, const float* __restrict__ wq,
    const float* __restrict__ wk, const float* __restrict__ wv,
    const float* __restrict__ wo, uint2* __restrict__ out)
{
  int b = blockIdx.x;
  const float4* src; uint2* dst; int i;
  if (b < 4096) {
    i = b * 256 + threadIdx.x; src = (const float4*)x; dst = out;
  } else {
    int s = (b - 4096) >> 10;
    i = ((b - 4096) & 1023) * 256 + threadIdx.x;
    src = (const float4*)(s == 0 ? wq : s == 1 ? wk : s == 2 ? wv : wo);
    dst = out + (size_t)1048576 + (size_t)s * 262144;
  }
  float4 v = src[i];
  uint2 r; r.x = pk2(v.x, v.y); r.y = pk2(v.z, v.w);
  dst[i] = r;
}

// ---------------- RoPE cos/sin table (fp64 for accuracy) ----------------
__global__ __launch_bounds__(256) void rope_tab_kernel(const int* __restrict__ tokpos, float2* __restrict__ tab) {
  int t = blockIdx.x * 256 + threadIdx.x;      // t in [0, 65536)
  int s = t >> 5, k = t & 31;
  double inv = pow(10000.0, -(double)(2 * k) / 64.0);
  double ang = (double)tokpos[s] * inv;
  tab[t] = make_float2((float)cos(ang), (float)sin(ang));
}

// ---------------- NT GEMM 128x128 tile, BK=64, 4 waves, dbuf unroll-2 ------
__global__ __launch_bounds__(256) void gemm_nt(
    const ushort_t* __restrict__ A, const ushort_t* __restrict__ W,
    const float2* __restrict__ tab,
    ushort_t* __restrict__ Qo, ushort_t* __restrict__ Ko, ushort_t* __restrict__ Vo,
    float* __restrict__ outf, int fused)
{
  __shared__ ushort_t lA[2][128 * 64];
  __shared__ ushort_t lB[2][128 * 64];
  const int tid = threadIdx.x;
  const int w = tid >> 6, l = tid & 63, lo = l & 15, hi = l >> 4;
  const int wr = (w >> 1) * 64, wc = (w & 1) * 64;
  const char* Ab = (const char*)A + (size_t)blockIdx.y * 128 * 2048;
  const char* Bb = (const char*)W + (size_t)blockIdx.x * 128 * 2048;
  f32x4 acc[4][4] = {};

  const int o0 = w * 1024 + l * 16;
  const int r0 = o0 >> 7;
  const int us = ((o0 >> 4) & 7) ^ (r0 & 7);
  const char* ap = Ab + (size_t)r0 * 2048 + us * 16;
  const char* bp = Bb + (size_t)r0 * 2048 + us * 16;

  auto stage = [&](char* dA, char* dB, const char* aq, const char* bq) {
    #pragma unroll
    for (int i = 0; i < 4; ++i) {           // rows r0 + 32*i
      gload16(aq + i * 65536, dA + w * 1024 + i * 4096);
      gload16(bq + i * 65536, dB + w * 1024 + i * 4096);
    }
  };
  auto comp = [&](const ushort_t* lAb, const ushort_t* lBb) {
    #pragma unroll
    for (int c = 0; c < 2; ++c) {
      bf16x8 af[4], wf[4];
      #pragma unroll
      for (int m = 0; m < 4; ++m) {
        int row = wr + m * 16 + lo;
        af[m] = *(const bf16x8*)((const char*)lAb + row * 128 + ((c * 64 + hi * 16) ^ ((row & 7) << 4)));
      }
      #pragma unroll
      for (int n = 0; n < 4; ++n) {
        int row = wc + n * 16 + lo;
        wf[n] = *(const bf16x8*)((const char*)lBb + row * 128 + ((c * 64 + hi * 16) ^ ((row & 7) << 4)));
      }
      #pragma unroll
      for (int m = 0; m < 4; ++m)
        #pragma unroll
        for (int n = 0; n < 4; ++n)
          acc[m][n] = mfma16(af[m], wf[n], acc[m][n]);
    }
  };

  stage((char*)lA[0], (char*)lB[0], ap, bp); ap += 128; bp += 128;
  __syncthreads();
  for (int it = 0; it < 16; it += 2) {
    stage((char*)lA[1], (char*)lB[1], ap, bp); ap += 128; bp += 128;
    comp(lA[0], lB[0]);
    __syncthreads();
    if (it + 2 < 16) { stage((char*)lA[0], (char*)lB[0], ap, bp); ap += 128; bp += 128; }
    comp(lA[1], lB[1]);
    __syncthreads();
  }

  const int mode = fused ? (blockIdx.x >> 3) : 3;
  const int colblk = fused ? (blockIdx.x & 7) : blockIdx.x;
  const int rowbase = blockIdx.y * 128 + wr + hi * 4;
  const int colbase = colblk * 128 + wc + lo;

  if (mode == 3) {
    #pragma unroll
    for (int m = 0; m < 4; ++m)
      #pragma unroll
      for (int n = 0; n < 4; ++n) {
        int e = colbase + n * 16;
        #pragma unroll
        for (int r = 0; r < 4; ++r) {
          int row = rowbase + m * 16 + r;
          outf[(size_t)row * 1024 + e] = acc[m][n][r];
        }
      }
    return;
  }
  if (mode == 2) {
    // V^T store with key-column permutation: within each 16-key group,
    // 4-blocks reordered [0-3][8-11][4-7][12-15] so attn's PV B-operand is
    // the natural post-QK P register layout (no cross-lane P exchange).
    #pragma unroll
    for (int m = 0; m < 4; ++m) {
      int row0 = rowbase + m * 16;
      int b = row0 >> 11, s = row0 & 2047;
      int b2 = (s >> 2) & 3;                               // 4-block index
      int sp = (s & ~12) | ((b2 & 1) << 3) | ((b2 >> 1) << 2);  // swap blks 1<->2
      #pragma unroll
      for (int n = 0; n < 4; ++n) {
        int e = colbase + n * 16;
        int h = e >> 6, dk = e & 63;
        uint2 pk;
        pk.x = pk2(acc[m][n][0], acc[m][n][1]);
        pk.y = pk2(acc[m][n][2], acc[m][n][3]);
        *(uint2*)(Vo + ((size_t)((b * NHEAD + h) * DKH + dk) * SEQ + sp)) = pk;
      }
    }
    return;
  }
  ushort_t* outb = (mode == 0) ? Qo : Ko;
  const float qscale = (mode == 0) ? (0.125f * LOG2E) : 1.0f;
  #pragma unroll
  for (int m = 0; m < 4; ++m) {
    #pragma unroll
    for (int n = 0; n < 4; ++n) {
      int e = colbase + n * 16;
      int h = e >> 6, dk = e & 63, kf = dk >> 1;
      float sgn = (e & 1) ? 1.0f : -1.0f;
      #pragma unroll
      for (int r = 0; r < 4; ++r) {
        int row = rowbase + m * 16 + r;
        int s = row & 2047, b = row >> 11;
        float2 cs = tab[s * 32 + kf];
        float v = acc[m][n][r];
        float p = __shfl_xor(v, 1, 64);
        float res = (v * cs.x + sgn * p * cs.y) * qscale;
        outb[((size_t)((b * NHEAD + h) * SEQ + s)) * DKH + dk] = b1(res);
      }
    }
  }
}

// ---------------- flash attention fwd: barrier-free, VALU-diet ------------
// Block = 64 queries, 4 waves each owning a disjoint 512-key quarter.
// Per-wave LDS dbuf + counted vmcnt + lgkmcnt WAR fence (R11, verified).
// R12: lsum via MFMA-with-ones (A=all-ones is layout-proof: D rows all equal
// sum_k P[k][q], col=query); hoisted fzero C-operand; sched_barriers removed
// (IR-level loads are ordered by the asm "memory" clobber).
__global__ __launch_bounds__(256) void attn_fwd(
    const ushort_t* __restrict__ Qg, const ushort_t* __restrict__ Kg,
    const ushort_t* __restrict__ VTg, ushort_t* __restrict__ attn)
{
  // main loop: wave w owns [w*16384, w*16384+16384): 2 slots of 8KB [K 4K|V 4K]
  // epilogue: accO dump 4 x 16KB at 0..65536, lsum at 65536 + w*512
  __shared__ char lds[67584];
  const int tid = threadIdx.x;                // 0..255
  const int w = tid >> 6, l = tid & 63;
  const int q31 = l & 31, hf = l >> 5, s7 = l & 7;
  const int bh = blockIdx.y;                  // 0..31
  const int q0 = blockIdx.x * 64;             // block's 64 queries
  const char* Kb = (const char*)Kg + (size_t)bh * 2048 * 128;   // key rows, 128B
  const char* Vb = (const char*)VTg + (size_t)bh * 64 * 4096;   // d rows, 4096B

  // Q fragments: qreg[qb][c] = Q[q0+qb*32+q31][c*16 + hf*8 .. +7]
  bf16x8 qreg[2][4];
  #pragma unroll
  for (int qb = 0; qb < 2; ++qb) {
    const ushort_t* qp = Qg + ((size_t)bh * 2048 + q0 + qb * 32 + q31) * 64 + hf * 8;
    #pragma unroll
    for (int c = 0; c < 4; ++c) qreg[qb][c] = *(const bf16x8*)(qp + c * 16);
  }

  f32x16 accO[2][2] = {};                     // [qb][db], partial over wave's keys
  f32x16 accL[2] = {};                        // [qb] lsum accumulator (MFMA-ones)
  const f32x16 fzero = {};                    // hoisted C-operand for QK
  const uint one2 = 0x3F803F80u;              // bf16 1.0 pair
  const uint4v uo = {one2, one2, one2, one2};
  const bf16x8 onesA = __builtin_bit_cast(bf16x8, uo);

  // per-wave LDS read addresses (row l&31, swizzled 32B col chunks)
  char* wlds = lds + w * 16384;
  const char* ra[4];
  #pragma unroll
  for (int c = 0; c < 4; ++c)
    ra[c] = wlds + q31 * 128 + ((c * 32 + hf * 16) ^ (s7 << 4));

  // per-lane staging sources (pre-inverse-swizzled for linear LDS dest)
  const int usw = (l & 7) ^ (l >> 3);         // swizzled 16B slot for this lane
  const int kb0 = w * 512;                    // wave's key base
  const char* kst = Kb + (size_t)(kb0 + (l >> 3)) * 128 + usw * 16;          // += 4096/step
  const char* vst = Vb + (size_t)((l >> 3) + (usw >> 2) * 32) * 4096
                       + (size_t)kb0 * 2 + (usw & 3) * 16;                   // += 64/step

  auto stageT = [&](int slot) {               // 8 gload16/wave: K 4KB + V 4KB
    char* sp = wlds + slot;
    #pragma unroll
    for (int i = 0; i < 4; ++i)
      gload16(kst + i * 1024, sp + i * 1024 + l * 16);          // K rows +8i
    #pragma unroll
    for (int i = 0; i < 4; ++i)
      gload16(vst + i * 32768, sp + 4096 + i * 1024 + l * 16);  // V d-rows +8i
    kst += 4096; vst += 64;
  };

  auto tileC = [&](int slot) {                // one 32-key tile
    const int bo = slot;
    bf16x8 kf[4];
    #pragma unroll
    for (int c = 0; c < 4; ++c)
      kf[c] = *(const bf16x8*)(ra[c] + bo);
    f32x16 s0 = mfma32(kf[0], qreg[0][0], fzero);
    f32x16 s1 = mfma32(kf[0], qreg[1][0], fzero);
    #pragma unroll
    for (int c = 1; c < 4; ++c) {
      s0 = mfma32(kf[c], qreg[0][c], s0);
      s1 = mfma32(kf[c], qreg[1][c], s1);
    }
    // p[r] <-> within-tile key (r&3) + 8*(r>>2) + 4*hf
    float p0[16], p1[16];
    #pragma unroll
    for (int r = 0; r < 16; ++r) { p0[r] = fexp2(s0[r]); p1[r] = fexp2(s1[r]); }
    // PV: B-operand = P registers directly (V key-cols pre-permuted);
    // lsum via MFMA with all-ones A (no scalar adds, no serial chain)
    #pragma unroll
    for (int kcl = 0; kcl < 2; ++kcl) {
      const float* a0 = p0 + kcl * 8;
      const float* a1 = p1 + kcl * 8;
      uint4v u0 = { pk2(a0[0], a0[1]), pk2(a0[2], a0[3]),
                    pk2(a0[4], a0[5]), pk2(a0[6], a0[7]) };
      uint4v u1 = { pk2(a1[0], a1[1]), pk2(a1[2], a1[3]),
                    pk2(a1[4], a1[5]), pk2(a1[6], a1[7]) };
      bf16x8 pb0 = __builtin_bit_cast(bf16x8, u0);
      bf16x8 pb1 = __builtin_bit_cast(bf16x8, u1);
      bf16x8 vf0 = *(const bf16x8*)(ra[kcl]     + bo + 4096);   // d 0..31
      bf16x8 vf1 = *(const bf16x8*)(ra[kcl + 2] + bo + 4096);   // d 32..63
      accO[0][0] = mfma32(vf0, pb0, accO[0][0]);
      accO[0][1] = mfma32(vf1, pb0, accO[0][1]);
      accO[1][0] = mfma32(vf0, pb1, accO[1][0]);
      accO[1][1] = mfma32(vf1, pb1, accO[1][1]);
      accL[0] = mfma32(onesA, pb0, accL[0]);
      accL[1] = mfma32(onesA, pb1, accL[1]);
    }
  };

  // 16 steps, per-wave dbuf, counted vmcnt — no cross-wave barriers.
  // lgkmcnt(0) before each overwriting stage: ds_reads of the slot have
  // RETURNED before new global_load_lds to it are issued (WAR-safe, R11).
  stageT(0);                                  // step 0 -> slot 0
  #pragma unroll 1
  for (int it = 0; it < 7; ++it) {            // steps 0..13
    asm volatile("s_waitcnt lgkmcnt(0)" ::: "memory");  // slot-1 reads done (prev iter)
    stageT(8192);
    asm volatile("s_waitcnt vmcnt(8)" ::: "memory");
    tileC(0);
    asm volatile("s_waitcnt lgkmcnt(0)" ::: "memory");  // slot-0 reads done
    stageT(0);
    asm volatile("s_waitcnt vmcnt(8)" ::: "memory");
    tileC(8192);
  }
  asm volatile("s_waitcnt lgkmcnt(0)" ::: "memory");    // slot-1 reads done
  stageT(8192);                               // step 15's data
  asm volatile("s_waitcnt vmcnt(8)" ::: "memory");
  tileC(0);                                   // step 14
  asm volatile("s_waitcnt vmcnt(0)" ::: "memory");
  tileC(8192);                                // step 15

  // -------- combine the 4 key-quarter partials (linear) --------
  __syncthreads();                            // all waves done with slots
  #pragma unroll
  for (int qb = 0; qb < 2; ++qb)
    #pragma unroll
    for (int db = 0; db < 2; ++db)
      #pragma unroll
      for (int c2 = 0; c2 < 4; ++c2) {
        int j = qb * 8 + db * 4 + c2;
        f32x4 v = { accO[qb][db][c2 * 4 + 0], accO[qb][db][c2 * 4 + 1],
                    accO[qb][db][c2 * 4 + 2], accO[qb][db][c2 * 4 + 3] };
        *(f32x4*)(lds + w * 16384 + j * 1024 + l * 16) = v;
      }
  // accL[qb][0]: per-query (col = l&31) full partial sum over this wave's keys
  *(float2*)(lds + 65536 + w * 512 + l * 8) = make_float2(accL[0][0], accL[1][0]);
  __syncthreads();

  // wave w reduces j-chunks w*4..w*4+3 across all 4 wave partials
  float lt0 = 0.f, lt1 = 0.f;
  #pragma unroll
  for (int wp = 0; wp < 4; ++wp) {
    float2 lo = *(const float2*)(lds + 65536 + wp * 512 + l * 8);
    lt0 += lo.x; lt1 += lo.y;
  }
  // NOTE: no shfl reduce — accL already holds the full per-query sum
  float inv0 = 1.0f / lt0, inv1 = 1.0f / lt1;
  int b = bh >> 4, head = bh & 15;
  #pragma unroll
  for (int jj = 0; jj < 4; ++jj) {
    int j = w * 4 + jj;
    int qb = j >> 3, db = (j >> 2) & 1, c2 = j & 3;
    f32x4 v = {0.f, 0.f, 0.f, 0.f};
    #pragma unroll
    for (int wp = 0; wp < 4; ++wp) {
      f32x4 u = *(const f32x4*)(lds + wp * 16384 + j * 1024 + l * 16);
      v[0] += u[0]; v[1] += u[1]; v[2] += u[2]; v[3] += u[3];
    }
    float inv = qb ? inv1 : inv0;
    int d0 = db * 32 + c2 * 8 + hf * 4;
    ushort_t* op = attn + (size_t)(b * 2048 + q0 + qb * 32 + q31) * 1024 + head * 64;
    uint2 pk;
    pk.x = pk2(v[0] * inv, v[1] * inv);
    pk.y = pk2(v[2] * inv, v[3] * inv);
    *(uint2*)(op + d0) = pk;
  }
}

// ---------------- launch ----------------
extern "C" void kernel_launch(void* const* d_in, const int* in_sizes, int n_in,
                              void* d_out, int out_size, void* d_ws, size_t ws_size,
                              hipStream_t stream) {
  const float* x  = (const float*)d_in[0];
  const int* tok  = (const int*)d_in[1];
  const float* wq = (const float*)d_in[2];
  const float* wk = (const float*)d_in[3];
  const float* wv = (const float*)d_in[4];
  const float* wo = (const float*)d_in[5];
  float* out = (float*)d_out;
  char* ws = (char*)d_ws;

  size_t off = 0;
  float2* tab = (float2*)(ws + off); off += (size_t)SEQ * 32 * sizeof(float2);   // 512 KB
  ushort_t* xb  = (ushort_t*)(ws + off); off += (size_t)MROWS * DMODEL * 2;      // 8 MB
  ushort_t* wqkv = (ushort_t*)(ws + off); off += (size_t)3 * DMODEL * DMODEL * 2; // 6 MB
  ushort_t* wob = (ushort_t*)(ws + off); off += (size_t)DMODEL * DMODEL * 2;     // 2 MB
  ushort_t* Qg  = (ushort_t*)(ws + off); off += (size_t)MROWS * DMODEL * 2;      // 8 MB
  ushort_t* Kg  = (ushort_t*)(ws + off); off += (size_t)MROWS * DMODEL * 2;      // 8 MB
  ushort_t* VTg = (ushort_t*)(ws + off); off += (size_t)MROWS * DMODEL * 2;      // 8 MB
  ushort_t* attnb = xb;  // alias: xb dead after projection GEMM
  if (ws_size < off) return;

  cvt_all<<<8192, 256, 0, stream>>>(x, wq, wk, wv, wo, (uint2*)xb);
  rope_tab_kernel<<<256, 256, 0, stream>>>(tok, tab);

  gemm_nt<<<dim3(24, 32), 256, 0, stream>>>(xb, wqkv, tab, Qg, Kg, VTg, nullptr, 1);

  attn_fwd<<<dim3(SEQ / 64, NBATCH * NHEAD), 256, 0, stream>>>(Qg, Kg, VTg, attnb);

  gemm_nt<<<dim3(8, 32), 256, 0, stream>>>(attnb, wob, nullptr, nullptr, nullptr, nullptr, out, 0);
}

// Round 13
// 122.156 us; speedup vs baseline: 1.1235x; 1.1235x over previous
//
#include <hip/hip_runtime.h>
#include <stdint.h>

typedef __bf16 bf16x8 __attribute__((ext_vector_type(8)));
typedef __bf16 bf16x2 __attribute__((ext_vector_type(2)));
typedef float f32x4 __attribute__((ext_vector_type(4)));
typedef float f32x16 __attribute__((ext_vector_type(16)));
typedef unsigned short ushort_t;
typedef unsigned int uint;
typedef uint uint4v __attribute__((ext_vector_type(4)));

#define SEQ    2048
#define DMODEL 1024
#define NHEAD  16
#define DKH    64
#define NBATCH 2
#define MROWS  (NBATCH*SEQ)   // 4096
#define LOG2E  1.44269504088896340736f

__device__ __forceinline__ uint pk2(float a, float b) {
  bf16x2 t; t[0] = (__bf16)a; t[1] = (__bf16)b;
  return __builtin_bit_cast(uint, t);
}
__device__ __forceinline__ ushort_t b1(float a) {
  return __builtin_bit_cast(ushort_t, (__bf16)a);
}
__device__ __forceinline__ float fexp2(float x) {
#if __has_builtin(__builtin_amdgcn_exp2f)
  return __builtin_amdgcn_exp2f(x);
#else
  return exp2f(x);
#endif
}

__device__ __forceinline__ void gload16(const void* g, void* l) {
  __builtin_amdgcn_global_load_lds(
      (const __attribute__((address_space(1))) void*)g,
      (__attribute__((address_space(3))) void*)l, 16, 0, 0);
}

__device__ __forceinline__ f32x4 mfma16(bf16x8 a, bf16x8 b, f32x4 c) {
  return __builtin_amdgcn_mfma_f32_16x16x32_bf16(a, b, c, 0, 0, 0);
}
__device__ __forceinline__ f32x16 mfma32(bf16x8 a, bf16x8 b, f32x16 c) {
  return __builtin_amdgcn_mfma_f32_32x32x16_bf16(a, b, c, 0, 0, 0);
}

// ------- fused fp32 -> bf16 convert + RoPE cos/sin table (one launch) -----
__global__ __launch_bounds__(256) void cvt_all(
    const float* __restrict__ x, const float* __restrict__ wq,
    const float* __restrict__ wk, const float* __restrict__ wv,
    const float* __restrict__ wo, const int* __restrict__ tokpos,
    uint2* __restrict__ out, float2* __restrict__ tab)
{
  int b = blockIdx.x;
  if (b >= 8192) {                            // rope table (fp64 for accuracy)
    int t = (b - 8192) * 256 + threadIdx.x;   // [0, 65536)
    int s = t >> 5, k = t & 31;
    double inv = pow(10000.0, -(double)(2 * k) / 64.0);
    double ang = (double)tokpos[s] * inv;
    tab[t] = make_float2((float)cos(ang), (float)sin(ang));
    return;
  }
  const float4* src; uint2* dst; int i;
  if (b < 4096) {
    i = b * 256 + threadIdx.x; src = (const float4*)x; dst = out;
  } else {
    int s = (b - 4096) >> 10;
    i = ((b - 4096) & 1023) * 256 + threadIdx.x;
    src = (const float4*)(s == 0 ? wq : s == 1 ? wk : s == 2 ? wv : wo);
    dst = out + (size_t)1048576 + (size_t)s * 262144;
  }
  float4 v = src[i];
  uint2 r; r.x = pk2(v.x, v.y); r.y = pk2(v.z, v.w);
  dst[i] = r;
}

// ---------------- NT GEMM 128x128 tile, BK=64, 4 waves --------------------
// Counted-vmcnt 2-slot schedule (T4): per K-step {stage next -> vmcnt(8) ->
// barrier -> comp -> barrier}. No vmcnt(0) drain in-loop: the publish
// barrier carries per-wave vmcnt(8) (own slot-writes landed => after the
// barrier all waves' writes landed); the post-comp barrier releases the slot
// for restaging (comp's ds_reads returned before their MFMAs issued).
__global__ __launch_bounds__(256) void gemm_nt(
    const ushort_t* __restrict__ A, const ushort_t* __restrict__ W,
    const float2* __restrict__ tab,
    ushort_t* __restrict__ Qo, ushort_t* __restrict__ Ko, ushort_t* __restrict__ Vo,
    float* __restrict__ outf, int fused)
{
  __shared__ ushort_t lA[2][128 * 64];
  __shared__ ushort_t lB[2][128 * 64];
  const int tid = threadIdx.x;
  const int w = tid >> 6, l = tid & 63, lo = l & 15, hi = l >> 4;
  const int wr = (w >> 1) * 64, wc = (w & 1) * 64;
  const char* Ab = (const char*)A + (size_t)blockIdx.y * 128 * 2048;
  const char* Bb = (const char*)W + (size_t)blockIdx.x * 128 * 2048;
  f32x4 acc[4][4] = {};

  const int o0 = w * 1024 + l * 16;
  const int r0 = o0 >> 7;
  const int us = ((o0 >> 4) & 7) ^ (r0 & 7);
  const char* ap = Ab + (size_t)r0 * 2048 + us * 16;
  const char* bp = Bb + (size_t)r0 * 2048 + us * 16;

  auto stage = [&](char* dA, char* dB, const char* aq, const char* bq) {
    #pragma unroll
    for (int i = 0; i < 4; ++i) {           // rows r0 + 32*i
      gload16(aq + i * 65536, dA + w * 1024 + i * 4096);
      gload16(bq + i * 65536, dB + w * 1024 + i * 4096);
    }
  };
  auto comp = [&](const ushort_t* lAb, const ushort_t* lBb) {
    #pragma unroll
    for (int c = 0; c < 2; ++c) {
      bf16x8 af[4], wf[4];
      #pragma unroll
      for (int m = 0; m < 4; ++m) {
        int row = wr + m * 16 + lo;
        af[m] = *(const bf16x8*)((const char*)lAb + row * 128 + ((c * 64 + hi * 16) ^ ((row & 7) << 4)));
      }
      #pragma unroll
      for (int n = 0; n < 4; ++n) {
        int row = wc + n * 16 + lo;
        wf[n] = *(const bf16x8*)((const char*)lBb + row * 128 + ((c * 64 + hi * 16) ^ ((row & 7) << 4)));
      }
      #pragma unroll
      for (int m = 0; m < 4; ++m)
        #pragma unroll
        for (int n = 0; n < 4; ++n)
          acc[m][n] = mfma16(af[m], wf[n], acc[m][n]);
    }
  };

  stage((char*)lA[0], (char*)lB[0], ap, bp); ap += 128; bp += 128;   // step 0
  #pragma unroll 1
  for (int it = 0; it < 8; ++it) {
    stage((char*)lA[1], (char*)lB[1], ap, bp); ap += 128; bp += 128; // step 2it+1
    asm volatile("s_waitcnt vmcnt(8)" ::: "memory");   // slot-0 writes landed
    __builtin_amdgcn_s_barrier();                      // publish slot 0
    asm volatile("" ::: "memory");
    comp(lA[0], lB[0]);
    __builtin_amdgcn_s_barrier();                      // release slot 0
    asm volatile("" ::: "memory");
    if (it < 7) {
      stage((char*)lA[0], (char*)lB[0], ap, bp); ap += 128; bp += 128; // step 2it+2
      asm volatile("s_waitcnt vmcnt(8)" ::: "memory"); // slot-1 writes landed
    } else {
      asm volatile("s_waitcnt vmcnt(0)" ::: "memory");
    }
    __builtin_amdgcn_s_barrier();                      // publish slot 1
    asm volatile("" ::: "memory");
    comp(lA[1], lB[1]);
    __builtin_amdgcn_s_barrier();                      // release slot 1
    asm volatile("" ::: "memory");
  }

  const int mode = fused ? (blockIdx.x >> 3) : 3;
  const int colblk = fused ? (blockIdx.x & 7) : blockIdx.x;
  const int rowbase = blockIdx.y * 128 + wr + hi * 4;
  const int colbase = colblk * 128 + wc + lo;

  if (mode == 3) {
    #pragma unroll
    for (int m = 0; m < 4; ++m)
      #pragma unroll
      for (int n = 0; n < 4; ++n) {
        int e = colbase + n * 16;
        #pragma unroll
        for (int r = 0; r < 4; ++r) {
          int row = rowbase + m * 16 + r;
          outf[(size_t)row * 1024 + e] = acc[m][n][r];
        }
      }
    return;
  }
  if (mode == 2) {
    // V^T store with key-column permutation: within each 16-key group,
    // 4-blocks reordered [0-3][8-11][4-7][12-15] so attn's PV B-operand is
    // the natural post-QK P register layout (no cross-lane P exchange).
    #pragma unroll
    for (int m = 0; m < 4; ++m) {
      int row0 = rowbase + m * 16;
      int b = row0 >> 11, s = row0 & 2047;
      int b2 = (s >> 2) & 3;                               // 4-block index
      int sp = (s & ~12) | ((b2 & 1) << 3) | ((b2 >> 1) << 2);  // swap blks 1<->2
      #pragma unroll
      for (int n = 0; n < 4; ++n) {
        int e = colbase + n * 16;
        int h = e >> 6, dk = e & 63;
        uint2 pk;
        pk.x = pk2(acc[m][n][0], acc[m][n][1]);
        pk.y = pk2(acc[m][n][2], acc[m][n][3]);
        *(uint2*)(Vo + ((size_t)((b * NHEAD + h) * DKH + dk) * SEQ + sp)) = pk;
      }
    }
    return;
  }
  ushort_t* outb = (mode == 0) ? Qo : Ko;
  const float qscale = (mode == 0) ? (0.125f * LOG2E) : 1.0f;
  #pragma unroll
  for (int m = 0; m < 4; ++m) {
    #pragma unroll
    for (int n = 0; n < 4; ++n) {
      int e = colbase + n * 16;
      int h = e >> 6, dk = e & 63, kf = dk >> 1;
      float sgn = (e & 1) ? 1.0f : -1.0f;
      #pragma unroll
      for (int r = 0; r < 4; ++r) {
        int row = rowbase + m * 16 + r;
        int s = row & 2047, b = row >> 11;
        float2 cs = tab[s * 32 + kf];
        float v = acc[m][n][r];
        float p = __shfl_xor(v, 1, 64);
        float res = (v * cs.x + sgn * p * cs.y) * qscale;
        outb[((size_t)((b * NHEAD + h) * SEQ + s)) * DKH + dk] = b1(res);
      }
    }
  }
}

// ---------------- flash attention fwd: barrier-free per-wave pipeline -----
// (R11 verbatim — verified 53.5 us / absmax 1.46e-3.)
// Block = 64 queries, 4 waves each owning a disjoint 512-key quarter
// (16 steps x 32 keys). Per-wave LDS double-buffer + counted vmcnt; no
// cross-wave barriers in the main loop. WAR fence: s_waitcnt lgkmcnt(0)
// before every slot-overwriting stage (ds_read completion is tracked by
// lgkmcnt, global_load_lds landing by vmcnt — no cross-counter ordering).
__global__ __launch_bounds__(256) void attn_fwd(
    const ushort_t* __restrict__ Qg, const ushort_t* __restrict__ Kg,
    const ushort_t* __restrict__ VTg, ushort_t* __restrict__ attn)
{
  // main loop: wave w owns [w*16384, w*16384+16384): 2 slots of 8KB [K 4K|V 4K]
  // epilogue: accO dump 4 x 16KB at 0..65536, lsum at 65536 + w*512
  __shared__ char lds[67584];
  const int tid = threadIdx.x;                // 0..255
  const int w = tid >> 6, l = tid & 63;
  const int q31 = l & 31, hf = l >> 5, s7 = l & 7;
  const int bh = blockIdx.y;                  // 0..31
  const int q0 = blockIdx.x * 64;             // block's 64 queries
  const char* Kb = (const char*)Kg + (size_t)bh * 2048 * 128;   // key rows, 128B
  const char* Vb = (const char*)VTg + (size_t)bh * 64 * 4096;   // d rows, 4096B

  // Q fragments: qreg[qb][c] = Q[q0+qb*32+q31][c*16 + hf*8 .. +7]
  bf16x8 qreg[2][4];
  #pragma unroll
  for (int qb = 0; qb < 2; ++qb) {
    const ushort_t* qp = Qg + ((size_t)bh * 2048 + q0 + qb * 32 + q31) * 64 + hf * 8;
    #pragma unroll
    for (int c = 0; c < 4; ++c) qreg[qb][c] = *(const bf16x8*)(qp + c * 16);
  }

  f32x16 accO[2][2] = {};                     // [qb][db], partial over wave's keys
  float lsum[2] = {0.f, 0.f};

  // per-wave LDS read addresses (row l&31, swizzled 32B col chunks)
  char* wlds = lds + w * 16384;
  const char* ra[4];
  #pragma unroll
  for (int c = 0; c < 4; ++c)
    ra[c] = wlds + q31 * 128 + ((c * 32 + hf * 16) ^ (s7 << 4));

  // per-lane staging sources (pre-inverse-swizzled for linear LDS dest)
  const int usw = (l & 7) ^ (l >> 3);         // swizzled 16B slot for this lane
  const int kb0 = w * 512;                    // wave's key base
  const char* kst = Kb + (size_t)(kb0 + (l >> 3)) * 128 + usw * 16;          // += 4096/step
  const char* vst = Vb + (size_t)((l >> 3) + (usw >> 2) * 32) * 4096
                       + (size_t)kb0 * 2 + (usw & 3) * 16;                   // += 64/step

  auto stageT = [&](int slot) {               // 8 gload16/wave: K 4KB + V 4KB
    char* sp = wlds + slot;
    #pragma unroll
    for (int i = 0; i < 4; ++i)
      gload16(kst + i * 1024, sp + i * 1024 + l * 16);          // K rows +8i
    #pragma unroll
    for (int i = 0; i < 4; ++i)
      gload16(vst + i * 32768, sp + 4096 + i * 1024 + l * 16);  // V d-rows +8i
    kst += 4096; vst += 64;
  };

  auto tileC = [&](int slot) {                // one 32-key tile
    const int bo = slot;
    bf16x8 kf[4];
    #pragma unroll
    for (int c = 0; c < 4; ++c)
      kf[c] = *(const bf16x8*)(ra[c] + bo);
    f32x16 s0 = {}, s1 = {};
    #pragma unroll
    for (int c = 0; c < 4; ++c) {
      s0 = mfma32(kf[c], qreg[0][c], s0);
      s1 = mfma32(kf[c], qreg[1][c], s1);
    }
    // p[r] <-> within-tile key (r&3) + 8*(r>>2) + 4*hf
    float p0[16], p1[16];
    float t0 = 0.f, t1 = 0.f;
    #pragma unroll
    for (int r = 0; r < 16; ++r) { p0[r] = fexp2(s0[r]); t0 += p0[r]; }
    #pragma unroll
    for (int r = 0; r < 16; ++r) { p1[r] = fexp2(s1[r]); t1 += p1[r]; }
    lsum[0] += t0; lsum[1] += t1;
    // PV: B-operand = P registers directly (V key-cols pre-permuted)
    #pragma unroll
    for (int kcl = 0; kcl < 2; ++kcl) {
      const float* a0 = p0 + kcl * 8;
      const float* a1 = p1 + kcl * 8;
      uint4v u0 = { pk2(a0[0], a0[1]), pk2(a0[2], a0[3]),
                    pk2(a0[4], a0[5]), pk2(a0[6], a0[7]) };
      uint4v u1 = { pk2(a1[0], a1[1]), pk2(a1[2], a1[3]),
                    pk2(a1[4], a1[5]), pk2(a1[6], a1[7]) };
      bf16x8 pb0 = __builtin_bit_cast(bf16x8, u0);
      bf16x8 pb1 = __builtin_bit_cast(bf16x8, u1);
      bf16x8 vf0 = *(const bf16x8*)(ra[kcl]     + bo + 4096);   // d 0..31
      bf16x8 vf1 = *(const bf16x8*)(ra[kcl + 2] + bo + 4096);   // d 32..63
      accO[0][0] = mfma32(vf0, pb0, accO[0][0]);
      accO[0][1] = mfma32(vf1, pb0, accO[0][1]);
      accO[1][0] = mfma32(vf0, pb1, accO[1][0]);
      accO[1][1] = mfma32(vf1, pb1, accO[1][1]);
    }
  };

  // 16 steps, per-wave dbuf, counted vmcnt — no cross-wave barriers.
  stageT(0);                                  // step 0 -> slot 0
  #pragma unroll 1
  for (int it = 0; it < 7; ++it) {            // steps 0..13
    asm volatile("s_waitcnt lgkmcnt(0)" ::: "memory");  // slot-1 reads done (prev iter)
    stageT(8192);
    asm volatile("s_waitcnt vmcnt(8)" ::: "memory");
    __builtin_amdgcn_sched_barrier(0);
    tileC(0);
    asm volatile("s_waitcnt lgkmcnt(0)" ::: "memory");  // slot-0 reads done
    stageT(0);
    asm volatile("s_waitcnt vmcnt(8)" ::: "memory");
    __builtin_amdgcn_sched_barrier(0);
    tileC(8192);
  }
  asm volatile("s_waitcnt lgkmcnt(0)" ::: "memory");    // slot-1 reads done
  stageT(8192);                               // step 15's data
  asm volatile("s_waitcnt vmcnt(8)" ::: "memory");
  __builtin_amdgcn_sched_barrier(0);
  tileC(0);                                   // step 14
  asm volatile("s_waitcnt vmcnt(0)" ::: "memory");
  __builtin_amdgcn_sched_barrier(0);
  tileC(8192);                                // step 15

  // -------- combine the 4 key-quarter partials (linear) --------
  __syncthreads();                            // all waves done with slots
  #pragma unroll
  for (int qb = 0; qb < 2; ++qb)
    #pragma unroll
    for (int db = 0; db < 2; ++db)
      #pragma unroll
      for (int c2 = 0; c2 < 4; ++c2) {
        int j = qb * 8 + db * 4 + c2;
        f32x4 v = { accO[qb][db][c2 * 4 + 0], accO[qb][db][c2 * 4 + 1],
                    accO[qb][db][c2 * 4 + 2], accO[qb][db][c2 * 4 + 3] };
        *(f32x4*)(lds + w * 16384 + j * 1024 + l * 16) = v;
      }
  *(float2*)(lds + 65536 + w * 512 + l * 8) = make_float2(lsum[0], lsum[1]);
  __syncthreads();

  // wave w reduces j-chunks w*4..w*4+3 across all 4 wave partials
  float lt0 = 0.f, lt1 = 0.f;
  #pragma unroll
  for (int wp = 0; wp < 4; ++wp) {
    float2 lo = *(const float2*)(lds + 65536 + wp * 512 + l * 8);
    lt0 += lo.x; lt1 += lo.y;
  }
  lt0 += __shfl_xor(lt0, 32, 64);
  lt1 += __shfl_xor(lt1, 32, 64);
  float inv0 = 1.0f / lt0, inv1 = 1.0f / lt1;
  int b = bh >> 4, head = bh & 15;
  #pragma unroll
  for (int jj = 0; jj < 4; ++jj) {
    int j = w * 4 + jj;
    int qb = j >> 3, db = (j >> 2) & 1, c2 = j & 3;
    f32x4 v = {0.f, 0.f, 0.f, 0.f};
    #pragma unroll
    for (int wp = 0; wp < 4; ++wp) {
      f32x4 u = *(const f32x4*)(lds + wp * 16384 + j * 1024 + l * 16);
      v[0] += u[0]; v[1] += u[1]; v[2] += u[2]; v[3] += u[3];
    }
    float inv = qb ? inv1 : inv0;
    int d0 = db * 32 + c2 * 8 + hf * 4;
    ushort_t* op = attn + (size_t)(b * 2048 + q0 + qb * 32 + q31) * 1024 + head * 64;
    uint2 pk;
    pk.x = pk2(v[0] * inv, v[1] * inv);
    pk.y = pk2(v[2] * inv, v[3] * inv);
    *(uint2*)(op + d0) = pk;
  }
}

// ---------------- launch ----------------
extern "C" void kernel_launch(void* const* d_in, const int* in_sizes, int n_in,
                              void* d_out, int out_size, void* d_ws, size_t ws_size,
                              hipStream_t stream) {
  const float* x  = (const float*)d_in[0];
  const int* tok  = (const int*)d_in[1];
  const float* wq = (const float*)d_in[2];
  const float* wk = (const float*)d_in[3];
  const float* wv = (const float*)d_in[4];
  const float* wo = (const float*)d_in[5];
  float* out = (float*)d_out;
  char* ws = (char*)d_ws;

  size_t off = 0;
  float2* tab = (float2*)(ws + off); off += (size_t)SEQ * 32 * sizeof(float2);   // 512 KB
  ushort_t* xb  = (ushort_t*)(ws + off); off += (size_t)MROWS * DMODEL * 2;      // 8 MB
  ushort_t* wqkv = (ushort_t*)(ws + off); off += (size_t)3 * DMODEL * DMODEL * 2; // 6 MB
  ushort_t* wob = (ushort_t*)(ws + off); off += (size_t)DMODEL * DMODEL * 2;     // 2 MB
  ushort_t* Qg  = (ushort_t*)(ws + off); off += (size_t)MROWS * DMODEL * 2;      // 8 MB
  ushort_t* Kg  = (ushort_t*)(ws + off); off += (size_t)MROWS * DMODEL * 2;      // 8 MB
  ushort_t* VTg = (ushort_t*)(ws + off); off += (size_t)MROWS * DMODEL * 2;      // 8 MB
  ushort_t* attnb = xb;  // alias: xb dead after projection GEMM
  if (ws_size < off) return;

  cvt_all<<<8448, 256, 0, stream>>>(x, wq, wk, wv, wo, tok, (uint2*)xb, tab);

  gemm_nt<<<dim3(24, 32), 256, 0, stream>>>(xb, wqkv, tab, Qg, Kg, VTg, nullptr, 1);

  attn_fwd<<<dim3(SEQ / 64, NBATCH * NHEAD), 256, 0, stream>>>(Qg, Kg, VTg, attnb);

  gemm_nt<<<dim3(8, 32), 256, 0, stream>>>(attnb, wob, nullptr, nullptr, nullptr, nullptr, out, 0);
}

// Round 14
// 118.980 us; speedup vs baseline: 1.1534x; 1.0267x over previous
//
#include <hip/hip_runtime.h>
#include <stdint.h>

typedef __bf16 bf16x8 __attribute__((ext_vector_type(8)));
typedef __bf16 bf16x2 __attribute__((ext_vector_type(2)));
typedef float f32x4 __attribute__((ext_vector_type(4)));
typedef float f32x16 __attribute__((ext_vector_type(16)));
typedef unsigned short ushort_t;
typedef unsigned int uint;
typedef uint uint4v __attribute__((ext_vector_type(4)));

#define SEQ    2048
#define DMODEL 1024
#define NHEAD  16
#define DKH    64
#define NBATCH 2
#define MROWS  (NBATCH*SEQ)   // 4096
#define LOG2E  1.44269504088896340736f

__device__ __forceinline__ uint pk2(float a, float b) {
  bf16x2 t; t[0] = (__bf16)a; t[1] = (__bf16)b;
  return __builtin_bit_cast(uint, t);
}
__device__ __forceinline__ ushort_t b1(float a) {
  return __builtin_bit_cast(ushort_t, (__bf16)a);
}
__device__ __forceinline__ float fexp2(float x) {
#if __has_builtin(__builtin_amdgcn_exp2f)
  return __builtin_amdgcn_exp2f(x);
#else
  return exp2f(x);
#endif
}

__device__ __forceinline__ void gload16(const void* g, void* l) {
  __builtin_amdgcn_global_load_lds(
      (const __attribute__((address_space(1))) void*)g,
      (__attribute__((address_space(3))) void*)l, 16, 0, 0);
}

__device__ __forceinline__ f32x4 mfma16(bf16x8 a, bf16x8 b, f32x4 c) {
  return __builtin_amdgcn_mfma_f32_16x16x32_bf16(a, b, c, 0, 0, 0);
}
__device__ __forceinline__ f32x16 mfma32(bf16x8 a, bf16x8 b, f32x16 c) {
  return __builtin_amdgcn_mfma_f32_32x32x16_bf16(a, b, c, 0, 0, 0);
}

// ------- fused fp32 -> bf16 convert + RoPE cos/sin table (one launch) -----
__global__ __launch_bounds__(256) void cvt_all(
    const float* __restrict__ x, const float* __restrict__ wq,
    const float* __restrict__ wk, const float* __restrict__ wv,
    const float* __restrict__ wo, const int* __restrict__ tokpos,
    uint2* __restrict__ out, float2* __restrict__ tab)
{
  int b = blockIdx.x;
  if (b >= 8192) {                            // rope table (fp64 for accuracy)
    int t = (b - 8192) * 256 + threadIdx.x;   // [0, 65536)
    int s = t >> 5, k = t & 31;
    double inv = pow(10000.0, -(double)(2 * k) / 64.0);
    double ang = (double)tokpos[s] * inv;
    tab[t] = make_float2((float)cos(ang), (float)sin(ang));
    return;
  }
  const float4* src; uint2* dst; int i;
  if (b < 4096) {
    i = b * 256 + threadIdx.x; src = (const float4*)x; dst = out;
  } else {
    int s = (b - 4096) >> 10;
    i = ((b - 4096) & 1023) * 256 + threadIdx.x;
    src = (const float4*)(s == 0 ? wq : s == 1 ? wk : s == 2 ? wv : wo);
    dst = out + (size_t)1048576 + (size_t)s * 262144;
  }
  float4 v = src[i];
  uint2 r; r.x = pk2(v.x, v.y); r.y = pk2(v.z, v.w);
  dst[i] = r;
}

// ---------------- NT GEMM 128x128 tile, BK=64, 4 waves --------------------
// Counted-vmcnt 2-slot schedule (R13, verified). R14: XCD-aware block
// swizzle (T1) — same-A-panel blocks land contiguously on one XCD's L2.
// nbx: virtual grid x-extent (24 fused / 8 WO); grid.x*grid.y divisible by 8.
__global__ __launch_bounds__(256) void gemm_nt(
    const ushort_t* __restrict__ A, const ushort_t* __restrict__ W,
    const float2* __restrict__ tab,
    ushort_t* __restrict__ Qo, ushort_t* __restrict__ Ko, ushort_t* __restrict__ Vo,
    float* __restrict__ outf, int fused, int nbx)
{
  __shared__ ushort_t lA[2][128 * 64];
  __shared__ ushort_t lB[2][128 * 64];
  const int tid = threadIdx.x;
  // XCD swizzle: lin%8 = XCD under round-robin dispatch; give each XCD a
  // contiguous chunk of the virtual (by-major) block order.
  const int lin = blockIdx.y * nbx + blockIdx.x;
  const int nwg = nbx * gridDim.y;
  const int n = (lin & 7) * (nwg >> 3) + (lin >> 3);
  const int vbx = n % nbx, vby = n / nbx;
  const int w = tid >> 6, l = tid & 63, lo = l & 15, hi = l >> 4;
  const int wr = (w >> 1) * 64, wc = (w & 1) * 64;
  const char* Ab = (const char*)A + (size_t)vby * 128 * 2048;
  const char* Bb = (const char*)W + (size_t)vbx * 128 * 2048;
  f32x4 acc[4][4] = {};

  const int o0 = w * 1024 + l * 16;
  const int r0 = o0 >> 7;
  const int us = ((o0 >> 4) & 7) ^ (r0 & 7);
  const char* ap = Ab + (size_t)r0 * 2048 + us * 16;
  const char* bp = Bb + (size_t)r0 * 2048 + us * 16;

  auto stage = [&](char* dA, char* dB, const char* aq, const char* bq) {
    #pragma unroll
    for (int i = 0; i < 4; ++i) {           // rows r0 + 32*i
      gload16(aq + i * 65536, dA + w * 1024 + i * 4096);
      gload16(bq + i * 65536, dB + w * 1024 + i * 4096);
    }
  };
  auto comp = [&](const ushort_t* lAb, const ushort_t* lBb) {
    #pragma unroll
    for (int c = 0; c < 2; ++c) {
      bf16x8 af[4], wf[4];
      #pragma unroll
      for (int m = 0; m < 4; ++m) {
        int row = wr + m * 16 + lo;
        af[m] = *(const bf16x8*)((const char*)lAb + row * 128 + ((c * 64 + hi * 16) ^ ((row & 7) << 4)));
      }
      #pragma unroll
      for (int n2 = 0; n2 < 4; ++n2) {
        int row = wc + n2 * 16 + lo;
        wf[n2] = *(const bf16x8*)((const char*)lBb + row * 128 + ((c * 64 + hi * 16) ^ ((row & 7) << 4)));
      }
      #pragma unroll
      for (int m = 0; m < 4; ++m)
        #pragma unroll
        for (int n2 = 0; n2 < 4; ++n2)
          acc[m][n2] = mfma16(af[m], wf[n2], acc[m][n2]);
    }
  };

  stage((char*)lA[0], (char*)lB[0], ap, bp); ap += 128; bp += 128;   // step 0
  #pragma unroll 1
  for (int it = 0; it < 8; ++it) {
    stage((char*)lA[1], (char*)lB[1], ap, bp); ap += 128; bp += 128; // step 2it+1
    asm volatile("s_waitcnt vmcnt(8)" ::: "memory");   // slot-0 writes landed
    __builtin_amdgcn_s_barrier();                      // publish slot 0
    asm volatile("" ::: "memory");
    comp(lA[0], lB[0]);
    __builtin_amdgcn_s_barrier();                      // release slot 0
    asm volatile("" ::: "memory");
    if (it < 7) {
      stage((char*)lA[0], (char*)lB[0], ap, bp); ap += 128; bp += 128; // step 2it+2
      asm volatile("s_waitcnt vmcnt(8)" ::: "memory"); // slot-1 writes landed
    } else {
      asm volatile("s_waitcnt vmcnt(0)" ::: "memory");
    }
    __builtin_amdgcn_s_barrier();                      // publish slot 1
    asm volatile("" ::: "memory");
    comp(lA[1], lB[1]);
    __builtin_amdgcn_s_barrier();                      // release slot 1
    asm volatile("" ::: "memory");
  }

  const int mode = fused ? (vbx >> 3) : 3;
  const int colblk = fused ? (vbx & 7) : vbx;
  const int rowbase = vby * 128 + wr + hi * 4;
  const int colbase = colblk * 128 + wc + lo;

  if (mode == 3) {
    #pragma unroll
    for (int m = 0; m < 4; ++m)
      #pragma unroll
      for (int n2 = 0; n2 < 4; ++n2) {
        int e = colbase + n2 * 16;
        #pragma unroll
        for (int r = 0; r < 4; ++r) {
          int row = rowbase + m * 16 + r;
          outf[(size_t)row * 1024 + e] = acc[m][n2][r];
        }
      }
    return;
  }
  if (mode == 2) {
    // V^T store with key-column permutation: within each 16-key group,
    // 4-blocks reordered [0-3][8-11][4-7][12-15] so attn's PV B-operand is
    // the natural post-QK P register layout (no cross-lane P exchange).
    #pragma unroll
    for (int m = 0; m < 4; ++m) {
      int row0 = rowbase + m * 16;
      int b = row0 >> 11, s = row0 & 2047;
      int b2 = (s >> 2) & 3;                               // 4-block index
      int sp = (s & ~12) | ((b2 & 1) << 3) | ((b2 >> 1) << 2);  // swap blks 1<->2
      #pragma unroll
      for (int n2 = 0; n2 < 4; ++n2) {
        int e = colbase + n2 * 16;
        int h = e >> 6, dk = e & 63;
        uint2 pk;
        pk.x = pk2(acc[m][n2][0], acc[m][n2][1]);
        pk.y = pk2(acc[m][n2][2], acc[m][n2][3]);
        *(uint2*)(Vo + ((size_t)((b * NHEAD + h) * DKH + dk) * SEQ + sp)) = pk;
      }
    }
    return;
  }
  ushort_t* outb = (mode == 0) ? Qo : Ko;
  const float qscale = (mode == 0) ? (0.125f * LOG2E) : 1.0f;
  #pragma unroll
  for (int m = 0; m < 4; ++m) {
    #pragma unroll
    for (int n2 = 0; n2 < 4; ++n2) {
      int e = colbase + n2 * 16;
      int h = e >> 6, dk = e & 63, kf = dk >> 1;
      float sgn = (e & 1) ? 1.0f : -1.0f;
      #pragma unroll
      for (int r = 0; r < 4; ++r) {
        int row = rowbase + m * 16 + r;
        int s = row & 2047, b = row >> 11;
        float2 cs = tab[s * 32 + kf];
        float v = acc[m][n2][r];
        float p = __shfl_xor(v, 1, 64);
        float res = (v * cs.x + sgn * p * cs.y) * qscale;
        outb[((size_t)((b * NHEAD + h) * SEQ + s)) * DKH + dk] = b1(res);
      }
    }
  }
}

// ---------------- flash attention fwd: barrier-free per-wave pipeline -----
// (R11 core — verified.) R14: XCD swizzle — each XCD gets 4 whole heads
// (128 consecutive virtual blocks), so K/V (2 MB per 4 heads) stays L2-
// resident instead of being refetched from HBM by scattered q-blocks.
__global__ __launch_bounds__(256) void attn_fwd(
    const ushort_t* __restrict__ Qg, const ushort_t* __restrict__ Kg,
    const ushort_t* __restrict__ VTg, ushort_t* __restrict__ attn)
{
  // main loop: wave w owns [w*16384, w*16384+16384): 2 slots of 8KB [K 4K|V 4K]
  // epilogue: accO dump 4 x 16KB at 0..65536, lsum at 65536 + w*512
  __shared__ char lds[67584];
  const int tid = threadIdx.x;                // 0..255
  const int w = tid >> 6, l = tid & 63;
  const int q31 = l & 31, hf = l >> 5, s7 = l & 7;
  // XCD swizzle: 1024 blocks = 8 XCDs x 128; virtual id n: bh = n>>5 (32
  // consecutive n share a head), qt = n&31.
  const int lin = blockIdx.y * gridDim.x + blockIdx.x;
  const int n = (lin & 7) * 128 + (lin >> 3);
  const int bh = n >> 5;                      // 0..31
  const int q0 = (n & 31) * 64;               // block's 64 queries
  const char* Kb = (const char*)Kg + (size_t)bh * 2048 * 128;   // key rows, 128B
  const char* Vb = (const char*)VTg + (size_t)bh * 64 * 4096;   // d rows, 4096B

  // Q fragments: qreg[qb][c] = Q[q0+qb*32+q31][c*16 + hf*8 .. +7]
  bf16x8 qreg[2][4];
  #pragma unroll
  for (int qb = 0; qb < 2; ++qb) {
    const ushort_t* qp = Qg + ((size_t)bh * 2048 + q0 + qb * 32 + q31) * 64 + hf * 8;
    #pragma unroll
    for (int c = 0; c < 4; ++c) qreg[qb][c] = *(const bf16x8*)(qp + c * 16);
  }

  f32x16 accO[2][2] = {};                     // [qb][db], partial over wave's keys
  float lsum[2] = {0.f, 0.f};

  // per-wave LDS read addresses (row l&31, swizzled 32B col chunks)
  char* wlds = lds + w * 16384;
  const char* ra[4];
  #pragma unroll
  for (int c = 0; c < 4; ++c)
    ra[c] = wlds + q31 * 128 + ((c * 32 + hf * 16) ^ (s7 << 4));

  // per-lane staging sources (pre-inverse-swizzled for linear LDS dest)
  const int usw = (l & 7) ^ (l >> 3);         // swizzled 16B slot for this lane
  const int kb0 = w * 512;                    // wave's key base
  const char* kst = Kb + (size_t)(kb0 + (l >> 3)) * 128 + usw * 16;          // += 4096/step
  const char* vst = Vb + (size_t)((l >> 3) + (usw >> 2) * 32) * 4096
                       + (size_t)kb0 * 2 + (usw & 3) * 16;                   // += 64/step

  auto stageT = [&](int slot) {               // 8 gload16/wave: K 4KB + V 4KB
    char* sp = wlds + slot;
    #pragma unroll
    for (int i = 0; i < 4; ++i)
      gload16(kst + i * 1024, sp + i * 1024 + l * 16);          // K rows +8i
    #pragma unroll
    for (int i = 0; i < 4; ++i)
      gload16(vst + i * 32768, sp + 4096 + i * 1024 + l * 16);  // V d-rows +8i
    kst += 4096; vst += 64;
  };

  auto tileC = [&](int slot) {                // one 32-key tile
    const int bo = slot;
    bf16x8 kf[4];
    #pragma unroll
    for (int c = 0; c < 4; ++c)
      kf[c] = *(const bf16x8*)(ra[c] + bo);
    f32x16 s0 = {}, s1 = {};
    #pragma unroll
    for (int c = 0; c < 4; ++c) {
      s0 = mfma32(kf[c], qreg[0][c], s0);
      s1 = mfma32(kf[c], qreg[1][c], s1);
    }
    // p[r] <-> within-tile key (r&3) + 8*(r>>2) + 4*hf
    float p0[16], p1[16];
    float t0 = 0.f, t1 = 0.f;
    #pragma unroll
    for (int r = 0; r < 16; ++r) { p0[r] = fexp2(s0[r]); t0 += p0[r]; }
    #pragma unroll
    for (int r = 0; r < 16; ++r) { p1[r] = fexp2(s1[r]); t1 += p1[r]; }
    lsum[0] += t0; lsum[1] += t1;
    // PV: B-operand = P registers directly (V key-cols pre-permuted)
    #pragma unroll
    for (int kcl = 0; kcl < 2; ++kcl) {
      const float* a0 = p0 + kcl * 8;
      const float* a1 = p1 + kcl * 8;
      uint4v u0 = { pk2(a0[0], a0[1]), pk2(a0[2], a0[3]),
                    pk2(a0[4], a0[5]), pk2(a0[6], a0[7]) };
      uint4v u1 = { pk2(a1[0], a1[1]), pk2(a1[2], a1[3]),
                    pk2(a1[4], a1[5]), pk2(a1[6], a1[7]) };
      bf16x8 pb0 = __builtin_bit_cast(bf16x8, u0);
      bf16x8 pb1 = __builtin_bit_cast(bf16x8, u1);
      bf16x8 vf0 = *(const bf16x8*)(ra[kcl]     + bo + 4096);   // d 0..31
      bf16x8 vf1 = *(const bf16x8*)(ra[kcl + 2] + bo + 4096);   // d 32..63
      accO[0][0] = mfma32(vf0, pb0, accO[0][0]);
      accO[0][1] = mfma32(vf1, pb0, accO[0][1]);
      accO[1][0] = mfma32(vf0, pb1, accO[1][0]);
      accO[1][1] = mfma32(vf1, pb1, accO[1][1]);
    }
  };

  // 16 steps, per-wave dbuf, counted vmcnt — no cross-wave barriers.
  // lgkmcnt(0) before each overwriting stage: ds_reads of the slot have
  // RETURNED before new global_load_lds to it are issued (WAR-safe, R11).
  stageT(0);                                  // step 0 -> slot 0
  #pragma unroll 1
  for (int it = 0; it < 7; ++it) {            // steps 0..13
    asm volatile("s_waitcnt lgkmcnt(0)" ::: "memory");  // slot-1 reads done (prev iter)
    stageT(8192);
    asm volatile("s_waitcnt vmcnt(8)" ::: "memory");
    __builtin_amdgcn_sched_barrier(0);
    tileC(0);
    asm volatile("s_waitcnt lgkmcnt(0)" ::: "memory");  // slot-0 reads done
    stageT(0);
    asm volatile("s_waitcnt vmcnt(8)" ::: "memory");
    __builtin_amdgcn_sched_barrier(0);
    tileC(8192);
  }
  asm volatile("s_waitcnt lgkmcnt(0)" ::: "memory");    // slot-1 reads done
  stageT(8192);                               // step 15's data
  asm volatile("s_waitcnt vmcnt(8)" ::: "memory");
  __builtin_amdgcn_sched_barrier(0);
  tileC(0);                                   // step 14
  asm volatile("s_waitcnt vmcnt(0)" ::: "memory");
  __builtin_amdgcn_sched_barrier(0);
  tileC(8192);                                // step 15

  // -------- combine the 4 key-quarter partials (linear) --------
  __syncthreads();                            // all waves done with slots
  #pragma unroll
  for (int qb = 0; qb < 2; ++qb)
    #pragma unroll
    for (int db = 0; db < 2; ++db)
      #pragma unroll
      for (int c2 = 0; c2 < 4; ++c2) {
        int j = qb * 8 + db * 4 + c2;
        f32x4 v = { accO[qb][db][c2 * 4 + 0], accO[qb][db][c2 * 4 + 1],
                    accO[qb][db][c2 * 4 + 2], accO[qb][db][c2 * 4 + 3] };
        *(f32x4*)(lds + w * 16384 + j * 1024 + l * 16) = v;
      }
  *(float2*)(lds + 65536 + w * 512 + l * 8) = make_float2(lsum[0], lsum[1]);
  __syncthreads();

  // wave w reduces j-chunks w*4..w*4+3 across all 4 wave partials
  float lt0 = 0.f, lt1 = 0.f;
  #pragma unroll
  for (int wp = 0; wp < 4; ++wp) {
    float2 lo = *(const float2*)(lds + 65536 + wp * 512 + l * 8);
    lt0 += lo.x; lt1 += lo.y;
  }
  lt0 += __shfl_xor(lt0, 32, 64);
  lt1 += __shfl_xor(lt1, 32, 64);
  float inv0 = 1.0f / lt0, inv1 = 1.0f / lt1;
  int b = bh >> 4, head = bh & 15;
  #pragma unroll
  for (int jj = 0; jj < 4; ++jj) {
    int j = w * 4 + jj;
    int qb = j >> 3, db = (j >> 2) & 1, c2 = j & 3;
    f32x4 v = {0.f, 0.f, 0.f, 0.f};
    #pragma unroll
    for (int wp = 0; wp < 4; ++wp) {
      f32x4 u = *(const f32x4*)(lds + wp * 16384 + j * 1024 + l * 16);
      v[0] += u[0]; v[1] += u[1]; v[2] += u[2]; v[3] += u[3];
    }
    float inv = qb ? inv1 : inv0;
    int d0 = db * 32 + c2 * 8 + hf * 4;
    ushort_t* op = attn + (size_t)(b * 2048 + q0 + qb * 32 + q31) * 1024 + head * 64;
    uint2 pk;
    pk.x = pk2(v[0] * inv, v[1] * inv);
    pk.y = pk2(v[2] * inv, v[3] * inv);
    *(uint2*)(op + d0) = pk;
  }
}

// ---------------- launch ----------------
extern "C" void kernel_launch(void* const* d_in, const int* in_sizes, int n_in,
                              void* d_out, int out_size, void* d_ws, size_t ws_size,
                              hipStream_t stream) {
  const float* x  = (const float*)d_in[0];
  const int* tok  = (const int*)d_in[1];
  const float* wq = (const float*)d_in[2];
  const float* wk = (const float*)d_in[3];
  const float* wv = (const float*)d_in[4];
  const float* wo = (const float*)d_in[5];
  float* out = (float*)d_out;
  char* ws = (char*)d_ws;

  size_t off = 0;
  float2* tab = (float2*)(ws + off); off += (size_t)SEQ * 32 * sizeof(float2);   // 512 KB
  ushort_t* xb  = (ushort_t*)(ws + off); off += (size_t)MROWS * DMODEL * 2;      // 8 MB
  ushort_t* wqkv = (ushort_t*)(ws + off); off += (size_t)3 * DMODEL * DMODEL * 2; // 6 MB
  ushort_t* wob = (ushort_t*)(ws + off); off += (size_t)DMODEL * DMODEL * 2;     // 2 MB
  ushort_t* Qg  = (ushort_t*)(ws + off); off += (size_t)MROWS * DMODEL * 2;      // 8 MB
  ushort_t* Kg  = (ushort_t*)(ws + off); off += (size_t)MROWS * DMODEL * 2;      // 8 MB
  ushort_t* VTg = (ushort_t*)(ws + off); off += (size_t)MROWS * DMODEL * 2;      // 8 MB
  ushort_t* attnb = xb;  // alias: xb dead after projection GEMM
  if (ws_size < off) return;

  cvt_all<<<8448, 256, 0, stream>>>(x, wq, wk, wv, wo, tok, (uint2*)xb, tab);

  gemm_nt<<<dim3(24, 32), 256, 0, stream>>>(xb, wqkv, tab, Qg, Kg, VTg, nullptr, 1, 24);

  attn_fwd<<<dim3(SEQ / 64, NBATCH * NHEAD), 256, 0, stream>>>(Qg, Kg, VTg, attnb);

  gemm_nt<<<dim3(8, 32), 256, 0, stream>>>(attnb, wob, nullptr, nullptr, nullptr, nullptr, out, 0, 8);
}